// Round 5
// baseline (173.749 us; speedup 1.0000x reference)
//
#include <hip/hip_runtime.h>

// x shape (B, T, A, D) = (256, 2048, 22, 2) fp32
#define BB 256
#define TT 2048
#define AD 44                 // A*D
#define AD4 11                // float4 chunks per (b,t) row
#define F4_PER_B (TT * AD4)   // 22528 float4 per batch
#define ELEMS 8               // float4 per thread in stream kernel
#define BLK_F4 (256 * ELEMS)  // 2048 float4 per block = F4_PER_B / 11
#define BLOCKS_PER_B 11
#define NBLK (BB * BLOCKS_PER_B)  // 2816 blocks
#define DET_ITERS (TT / 256)      // 8 t's per thread in detect

typedef float v4 __attribute__((ext_vector_type(4)));

// Kernel 1: per-batch gap detection (channel-0 probe; NaN mask is identical
// across all 44 channels) + endpoint-row capture into ws.
__global__ __launch_bounds__(256) void detect(const float* __restrict__ x,
                                              int* __restrict__ starts,
                                              int* __restrict__ ends,
                                              v4* __restrict__ xs4,
                                              v4* __restrict__ xe4) {
  const int b = blockIdx.x;
  const int tid = threadIdx.x;
  const float* row = x + (size_t)b * TT * AD;

  int lmin = TT, lmax = -1;
#pragma unroll
  for (int j = 0; j < DET_ITERS; ++j) {
    const int t = tid + 256 * j;
    const float v = row[(size_t)t * AD];   // channel (a=0,d=0); lines L3-hot
    if (v != v) {
      lmin = min(lmin, t);
      lmax = max(lmax, t);
    }
  }

  __shared__ int smin[256], smax[256];
  smin[tid] = lmin;
  smax[tid] = lmax;
  __syncthreads();
  for (int s = 128; s > 0; s >>= 1) {
    if (tid < s) {
      smin[tid] = min(smin[tid], smin[tid + s]);
      smax[tid] = max(smax[tid], smax[tid + s]);
    }
    __syncthreads();
  }

  __shared__ int s_start, s_end;
  if (tid == 0) {
    s_start = smin[0] - 1;   // index before first NaN
    s_end   = smax[0] + 1;   // index after last NaN
    starts[b] = s_start;
    ends[b]   = s_end;
  }
  __syncthreads();

  const v4* row4 = (const v4*)row;
  if (tid < AD4) xs4[b * AD4 + tid] = row4[(size_t)s_start * AD4 + tid];
  if (tid >= 64 && tid < 64 + AD4)
    xe4[b * AD4 + (tid - 64)] = row4[(size_t)s_end * AD4 + (tid - 64)];
}

// Kernel 2: single streaming pass producing final out: copy outside the gap,
// interpolate inside. 8 float4/thread; a block covers 2048 consecutive float4
// = 1/11 of a batch, so b (and s,e) are block-uniform scalars.
__global__ __launch_bounds__(256) void stream(const v4* __restrict__ x4,
                                              v4* __restrict__ out4,
                                              const int* __restrict__ starts,
                                              const int* __restrict__ ends,
                                              const v4* __restrict__ xs4,
                                              const v4* __restrict__ xe4) {
  const int tid = threadIdx.x;
  const int b = blockIdx.x / BLOCKS_PER_B;
  const int blk_in_b = blockIdx.x - b * BLOCKS_PER_B;
  const int base_in_b = blk_in_b * BLK_F4;
  const size_t base = (size_t)b * F4_PER_B + base_in_b;

  // Issue all loads up front.
  v4 v[ELEMS];
#pragma unroll
  for (int k = 0; k < ELEMS; ++k) v[k] = x4[base + k * 256 + tid];

  const int s = starts[b];                 // scalar loads (b block-uniform)
  const int e = ends[b];
  const float inv = 1.0f / (float)(e - s);

#pragma unroll
  for (int k = 0; k < ELEMS; ++k) {
    const int off = base_in_b + k * 256 + tid;
    const int t = off / AD4;               // magic-mul const div
    if (t > s && t < e) {                  // rare; divergence is cheap
      const int c = off - t * AD4;
      const float w = (float)(t - s) * inv;
      const float om = 1.0f - w;
      const v4 a = xs4[b * AD4 + c];       // 45 KB ws: L1/L2-hot
      const v4 z = xe4[b * AD4 + c];
      v[k].x = a.x * om + z.x * w;
      v[k].y = a.y * om + z.y * w;
      v[k].z = a.z * om + z.z * w;
      v[k].w = a.w * om + z.w * w;
    }
    out4[base + k * 256 + tid] = v[k];
  }
}

extern "C" void kernel_launch(void* const* d_in, const int* in_sizes, int n_in,
                              void* d_out, int out_size, void* d_ws, size_t ws_size,
                              hipStream_t stream_) {
  const float* x = (const float*)d_in[0];
  v4* out4 = (v4*)d_out;

  // ws layout: [0,1KB) starts (256 int), [1KB,2KB) ends (256 int),
  //            [2KB, +45056B) xs4, then xe4.
  char* ws = (char*)d_ws;
  int* starts = (int*)ws;
  int* ends = (int*)(ws + 1024);
  v4* xs4 = (v4*)(ws + 2048);
  v4* xe4 = (v4*)(ws + 2048 + BB * AD4 * sizeof(v4));

  detect<<<BB, 256, 0, stream_>>>(x, starts, ends, xs4, xe4);
  stream<<<NBLK, 256, 0, stream_>>>((const v4*)x, out4, starts, ends, xs4, xe4);
}

// Round 6
// 173.347 us; speedup vs baseline: 1.0023x; 1.0023x over previous
//
#include <hip/hip_runtime.h>

// x shape (B, T, A, D) = (256, 2048, 22, 2) fp32
#define BB 256
#define TT 2048
#define AD 44                 // A*D
#define AD4 11                // float4 chunks per (b,t) row
#define F4_PER_B (TT * AD4)   // 22528 float4 per batch
#define ELEMS 8               // float4 per thread in stream kernel
#define BLK_F4 (256 * ELEMS)  // 2048 float4 per block = F4_PER_B / 11
#define BLOCKS_PER_B 11
#define NBLK (BB * BLOCKS_PER_B)  // 2816 blocks
#define DET_ITERS (TT / 256)      // 8 t's per thread in detect

typedef float v4 __attribute__((ext_vector_type(4)));

// Kernel 1: per-batch gap detection (channel-0 probe; NaN mask is identical
// across all 44 channels) + endpoint-row capture into ws.
__global__ __launch_bounds__(256) void detect(const float* __restrict__ x,
                                              int* __restrict__ starts,
                                              int* __restrict__ ends,
                                              v4* __restrict__ xs4,
                                              v4* __restrict__ xe4) {
  const int b = blockIdx.x;
  const int tid = threadIdx.x;
  const float* row = x + (size_t)b * TT * AD;

  int lmin = TT, lmax = -1;
#pragma unroll
  for (int j = 0; j < DET_ITERS; ++j) {
    const int t = tid + 256 * j;
    const float v = row[(size_t)t * AD];   // channel (a=0,d=0)
    if (v != v) {
      lmin = min(lmin, t);
      lmax = max(lmax, t);
    }
  }

  __shared__ int smin[256], smax[256];
  smin[tid] = lmin;
  smax[tid] = lmax;
  __syncthreads();
  for (int s = 128; s > 0; s >>= 1) {
    if (tid < s) {
      smin[tid] = min(smin[tid], smin[tid + s]);
      smax[tid] = max(smax[tid], smax[tid + s]);
    }
    __syncthreads();
  }

  __shared__ int s_start, s_end;
  if (tid == 0) {
    s_start = smin[0] - 1;   // index before first NaN
    s_end   = smax[0] + 1;   // index after last NaN
    starts[b] = s_start;
    ends[b]   = s_end;
  }
  __syncthreads();

  const v4* row4 = (const v4*)row;
  if (tid < AD4) xs4[b * AD4 + tid] = row4[(size_t)s_start * AD4 + tid];
  if (tid >= 64 && tid < 64 + AD4)
    xe4[b * AD4 + (tid - 64)] = row4[(size_t)s_end * AD4 + (tid - 64)];
}

// Kernel 2: single streaming pass producing final out: copy outside the gap,
// interpolate inside. 8 float4/thread, loads hard-fenced before stores via
// sched_barrier(0) so all 8 global_load_dwordx4 stay outstanding together.
__global__ __launch_bounds__(256) void stream(const v4* __restrict__ x4,
                                              v4* __restrict__ out4,
                                              const int* __restrict__ starts,
                                              const int* __restrict__ ends,
                                              const v4* __restrict__ xs4,
                                              const v4* __restrict__ xe4) {
  const int tid = threadIdx.x;
  const int b = blockIdx.x / BLOCKS_PER_B;
  const int blk_in_b = blockIdx.x - b * BLOCKS_PER_B;
  const int base_in_b = blk_in_b * BLK_F4;
  const size_t base = (size_t)b * F4_PER_B + base_in_b;

  // Scalar metadata first (b block-uniform -> s_load, L2-hot).
  const int s = starts[b];
  const int e = ends[b];
  const float inv = 1.0f / (float)(e - s);

  // Issue all 8 vector loads; nothing may be scheduled across the fence,
  // so all 8 stay in flight together (forces ~32 data VGPRs).
  v4 v[ELEMS];
#pragma unroll
  for (int k = 0; k < ELEMS; ++k) v[k] = x4[base + k * 256 + tid];
  __builtin_amdgcn_sched_barrier(0);

#pragma unroll
  for (int k = 0; k < ELEMS; ++k) {
    const int off = base_in_b + k * 256 + tid;
    const int t = off / AD4;               // magic-mul const div
    if (t > s && t < e) {                  // rare; divergence is cheap
      const int c = off - t * AD4;
      const float w = (float)(t - s) * inv;
      const float om = 1.0f - w;
      const v4 a = xs4[b * AD4 + c];       // 45 KB ws: L1/L2-hot
      const v4 z = xe4[b * AD4 + c];
      v[k].x = a.x * om + z.x * w;
      v[k].y = a.y * om + z.y * w;
      v[k].z = a.z * om + z.z * w;
      v[k].w = a.w * om + z.w * w;
    }
    out4[base + k * 256 + tid] = v[k];
  }
}

extern "C" void kernel_launch(void* const* d_in, const int* in_sizes, int n_in,
                              void* d_out, int out_size, void* d_ws, size_t ws_size,
                              hipStream_t stream_) {
  const float* x = (const float*)d_in[0];
  v4* out4 = (v4*)d_out;

  // ws layout: [0,1KB) starts (256 int), [1KB,2KB) ends (256 int),
  //            [2KB, +45056B) xs4, then xe4.
  char* ws = (char*)d_ws;
  int* starts = (int*)ws;
  int* ends = (int*)(ws + 1024);
  v4* xs4 = (v4*)(ws + 2048);
  v4* xe4 = (v4*)(ws + 2048 + BB * AD4 * sizeof(v4));

  detect<<<BB, 256, 0, stream_>>>(x, starts, ends, xs4, xe4);
  stream<<<NBLK, 256, 0, stream_>>>((const v4*)x, out4, starts, ends, xs4, xe4);
}